// Round 4
// baseline (6019.919 us; speedup 1.0000x reference)
//
#include <hip/hip_runtime.h>
#include <hip/hip_bf16.h>

// ShiftReduceCompressor: persistent kernel, 1 block per batch row (B=64),
// full 32-iteration scan inside the kernel. Encoder in fp32; sampling-critical
// tail (proj/GRU/heads/logits) in fp64. JAX threefry with PARTITIONABLE
// semantics (jax>=0.5 default): split(key,n)[i] = tfry(key,(0,i)) full pair;
// random_bits 32 = o0^o1 of tfry(key,(0,idx)). No d_ws usage.

#define XS 132   // x / obuf row stride (floats, 16B-aligned)
#define QS 388   // qkv row stride
#define HS 516   // ffn hidden row stride
#define PS 36    // prob row stride

struct KParams {
  const int* token_ids;
  const unsigned char* pad;
  const void *tok_emb, *pos_emb, *Wqkv, *bqkv, *Wo, *bo, *ln1g, *ln1b;
  const void *W1, *b1, *W2, *b2, *ln2g, *ln2b, *projW, *projb;
  const void *gWih, *gWhh, *gbih, *gbhh;
  const void *accW1, *accb1, *accW2, *accb2;
  const void *emtW1, *emtb1, *emtW2, *emtb2;
  const void *evtW1, *evtb1, *evtW2, *evtb2;
  float* out;
};

struct Smem {
  float xbuf[32 * XS];
  float qh[32 * HS];
  float obuf[32 * XS];
  float pbuf[4608];
  float attT[128];
  float tva[128];
  double gild[384];
  double ghld[384];
  double hsd[128];
  double t1d[64];
  double catd[320];
  double hid2d[128];
  double logitsd[3];
  int win_ids[32];
  int sI[6];                 // 0 win_len, 1 input_pos, 2 done, 3 seq_len, 4 emit_sum
  unsigned keyts[32][2];
};

// ---------- typed weight loads (f32 or bf16) ----------
__device__ __forceinline__ float ldw(const float* p){ return *p; }
__device__ __forceinline__ float ldw(const unsigned short* p){
  return __uint_as_float(((unsigned)*p) << 16);
}
__device__ __forceinline__ float4 ld4(const float* p){ return *(const float4*)p; }
__device__ __forceinline__ float4 ld4(const unsigned short* p){
  ushort4 u = *(const ushort4*)p;
  return make_float4(__uint_as_float((unsigned)u.x << 16),
                     __uint_as_float((unsigned)u.y << 16),
                     __uint_as_float((unsigned)u.z << 16),
                     __uint_as_float((unsigned)u.w << 16));
}
template<typename WT>
__device__ __forceinline__ double ldwd(const WT* p){ return (double)ldw(p); }

// ---------- JAX threefry2x32 (20 rounds) ----------
__device__ __forceinline__ void tfry(unsigned k0, unsigned k1, unsigned x0, unsigned x1,
                                     unsigned &o0, unsigned &o1){
  unsigned ks2 = k0 ^ k1 ^ 0x1BD11BDAu;
  unsigned x = x0 + k0, y = x1 + k1;
#define TFR(r) { x += y; y = (y << r) | (y >> (32 - r)); y ^= x; }
  TFR(13) TFR(15) TFR(26) TFR(6)  x += k1;  y += ks2 + 1u;
  TFR(17) TFR(29) TFR(16) TFR(24) x += ks2; y += k0 + 2u;
  TFR(13) TFR(15) TFR(26) TFR(6)  x += k0;  y += k1 + 3u;
  TFR(17) TFR(29) TFR(16) TFR(24) x += k1;  y += ks2 + 4u;
  TFR(13) TFR(15) TFR(26) TFR(6)  x += ks2; y += k0 + 5u;
#undef TFR
  o0 = x; o1 = y;
}

__device__ __forceinline__ float u01(unsigned bits){
  return __uint_as_float((bits >> 9) | 0x3f800000u) - 1.0f;
}
__device__ __forceinline__ double logsigd(double x){
  return fmin(x, 0.0) - log1p(exp(-fabs(x)));
}
__device__ __forceinline__ float wredsum(float v, int width){
  for (int m = width >> 1; m > 0; m >>= 1) v += __shfl_xor(v, m, width);
  return v;
}
__device__ __forceinline__ double wredsumd(double v, int width){
  for (int m = width >> 1; m > 0; m >>= 1) v += __shfl_xor(v, m, width);
  return v;
}
__device__ __forceinline__ float dot4f(float4 a, float4 b){
  return a.x*b.x + a.y*b.y + a.z*b.z + a.w*b.w;
}

// out[tok][j] = bias[j] + sum_k W[j][k]*x[tok][k]; lane=j mod 64, J2 ch/thread.
template<int J2, int T, int K, bool RELU, typename WT>
__device__ void gemm_tok(const WT* __restrict__ Wm, const WT* __restrict__ bias,
                         int J, const float* __restrict__ xl, int xs,
                         float* __restrict__ ol, int os, int ntok, int tid)
{
  const int lane = tid & 63, wid = tid >> 6;
  const int JBG = J / (64 * J2);
  const int ntt = (ntok + T - 1) / T;
  for (int item = wid; item < JBG * ntt; item += 4) {
    const int jg = item % JBG, tt = item / JBG;
    const int j0 = jg * 64 * J2 + lane;
    float acc[J2][T];
#pragma unroll
    for (int u = 0; u < J2; ++u)
#pragma unroll
      for (int t = 0; t < T; ++t) acc[u][t] = 0.f;
    const float* xr = xl + tt * T * xs;
#pragma unroll 4
    for (int k = 0; k < K; k += 4) {
      float4 xv[T];
#pragma unroll
      for (int t = 0; t < T; ++t) xv[t] = *(const float4*)(xr + t * xs + k);
#pragma unroll
      for (int u = 0; u < J2; ++u) {
        float4 w = ld4(Wm + (j0 + u * 64) * K + k);
#pragma unroll
        for (int t = 0; t < T; ++t)
          acc[u][t] += w.x * xv[t].x + w.y * xv[t].y + w.z * xv[t].z + w.w * xv[t].w;
      }
    }
#pragma unroll
    for (int u = 0; u < J2; ++u) {
      float bj = ldw(bias + j0 + u * 64);
#pragma unroll
      for (int t = 0; t < T; ++t) {
        int tok = tt * T + t;
        if (tok < ntok) {
          float v = acc[u][t] + bj;
          if (RELU) v = fmaxf(v, 0.f);
          ol[tok * os + j0 + u * 64] = v;
        }
      }
    }
  }
}

template<int K, typename WT>
__device__ __forceinline__ float dotgf(const WT* __restrict__ w, const float* x){
  float acc = 0.f;
#pragma unroll 8
  for (int k = 0; k < K; k += 4) {
    float4 wv = ld4(w + k);
    acc += wv.x * x[k] + wv.y * x[k+1] + wv.z * x[k+2] + wv.w * x[k+3];
  }
  return acc;
}
template<int K, typename WT>
__device__ __forceinline__ double dotgd(const WT* __restrict__ w, const double* x){
  double acc = 0.0;
#pragma unroll 4
  for (int k = 0; k < K; k += 4) {
    float4 wv = ld4(w + k);
    acc += (double)wv.x * x[k] + (double)wv.y * x[k+1]
         + (double)wv.z * x[k+2] + (double)wv.w * x[k+3];
  }
  return acc;
}
template<int K, typename WT>
__device__ __forceinline__ double dotgdx(const WT* __restrict__ w, const float* x){
  double acc = 0.0;
#pragma unroll 4
  for (int k = 0; k < K; k += 4) {
    float4 wv = ld4(w + k);
    acc += (double)wv.x * (double)x[k] + (double)wv.y * (double)x[k+1]
         + (double)wv.z * (double)x[k+2] + (double)wv.w * (double)x[k+3];
  }
  return acc;
}

// post-norm LN over D=128 for rows <W, y = x + o, 8 threads/row.
template<typename WT>
__device__ void ln_rows(float* xb, const float* ob, const WT* __restrict__ g,
                        const WT* __restrict__ bb, int W, int tid){
  const int i = tid >> 3, sub = tid & 7;
  const int base = i * XS + sub * 16;
  float y[16];
  float s = 0.f;
#pragma unroll
  for (int u = 0; u < 16; ++u) { y[u] = xb[base + u] + ob[base + u]; s += y[u]; }
  s = wredsum(s, 8);
  const float m = s * (1.0f / 128.0f);
  float vs = 0.f;
#pragma unroll
  for (int u = 0; u < 16; ++u) { float d = y[u] - m; vs += d * d; }
  vs = wredsum(vs, 8);
  const float rstd = 1.0f / sqrtf(vs * (1.0f / 128.0f) + 1e-5f);
  if (i < W) {
#pragma unroll
    for (int u = 0; u < 16; ++u)
      xb[base + u] = (y[u] - m) * rstd * ldw(g + sub * 16 + u) + ldw(bb + sub * 16 + u);
  }
}

template<typename WT>
__device__ __forceinline__ void ln_tail(float* xrow, const float* add,
                                        const WT* __restrict__ g,
                                        const WT* __restrict__ bb, int tid){
  if (tid < 64) {
    float y0 = xrow[tid] + add[tid];
    float y1 = xrow[64 + tid] + add[64 + tid];
    float m = wredsum(y0 + y1, 64) * (1.0f / 128.0f);
    float d0 = y0 - m, d1 = y1 - m;
    float rstd = 1.0f / sqrtf(wredsum(d0 * d0 + d1 * d1, 64) * (1.0f / 128.0f) + 1e-5f);
    xrow[tid] = d0 * rstd * ldw(g + tid) + ldw(bb + tid);
    xrow[64 + tid] = d1 * rstd * ldw(g + 64 + tid) + ldw(bb + 64 + tid);
  }
}

template<typename WT>
__device__ __forceinline__ void head_logit(const WT* __restrict__ w2, const WT* __restrict__ b2p,
                                           const double* hid, double* dst, int tid){
  if (tid < 64) {
    double pp = hid[tid] * ldwd(w2 + tid) + hid[tid + 64] * ldwd(w2 + tid + 64);
    pp = wredsumd(pp, 64);
    if (tid == 0) *dst = pp + ldwd(b2p);
  }
}

template<typename WT>
__device__ void run_all(const KParams& P, Smem& S, int row, int tid){
  const WT* tok_emb = (const WT*)P.tok_emb;
  const WT* pos_emb = (const WT*)P.pos_emb;
  const WT* Wqkv = (const WT*)P.Wqkv;   const WT* bqkv = (const WT*)P.bqkv;
  const WT* Wo = (const WT*)P.Wo;       const WT* bo = (const WT*)P.bo;
  const WT* ln1g = (const WT*)P.ln1g;   const WT* ln1b = (const WT*)P.ln1b;
  const WT* W1 = (const WT*)P.W1;       const WT* b1 = (const WT*)P.b1;
  const WT* W2 = (const WT*)P.W2;       const WT* b2 = (const WT*)P.b2;
  const WT* ln2g = (const WT*)P.ln2g;   const WT* ln2b = (const WT*)P.ln2b;
  const WT* projW = (const WT*)P.projW; const WT* projb = (const WT*)P.projb;
  const WT* gWih = (const WT*)P.gWih;   const WT* gWhh = (const WT*)P.gWhh;
  const WT* gbih = (const WT*)P.gbih;   const WT* gbhh = (const WT*)P.gbhh;
  const WT* accW1 = (const WT*)P.accW1; const WT* accb1 = (const WT*)P.accb1;
  const WT* accW2 = (const WT*)P.accW2; const WT* accb2 = (const WT*)P.accb2;
  const WT* emtW1 = (const WT*)P.emtW1; const WT* emtb1 = (const WT*)P.emtb1;
  const WT* emtW2 = (const WT*)P.emtW2; const WT* emtb2 = (const WT*)P.emtb2;
  const WT* evtW1 = (const WT*)P.evtW1; const WT* evtb1 = (const WT*)P.evtb1;
  const WT* evtW2 = (const WT*)P.evtW2; const WT* evtb2 = (const WT*)P.evtb2;

  // ---- init ----
  if (tid == 0) {
    int seq = 0;
    for (int l = 0; l < 64; ++l) seq += (P.pad[row * 64 + l] == 0);
    S.sI[0] = 0; S.sI[1] = 0; S.sI[2] = (seq == 0) ? 1 : 0; S.sI[3] = seq; S.sI[4] = 0;
  }
  for (int k = tid; k < 128; k += 256) S.hsd[k] = 0.0;
  for (int k = tid; k < 32; k += 256) S.win_ids[k] = 0;
  // PARTITIONABLE split: keys[t] = full (o0,o1) of tfry(key(0,42), (0, t))
  if (tid < 32) {
    unsigned a0, a1;
    tfry(0u, 42u, 0u, (unsigned)tid, a0, a1);
    S.keyts[tid][0] = a0; S.keyts[tid][1] = a1;
  }
  __syncthreads();

  for (int t = 0; t < 32; ++t) {
    const int wl = S.sI[0], ip = S.sI[1], done = S.sI[2], seq = S.sI[3];
    const int act = !done;
    const int W = wl;
    const int enc = (act && wl > 0) ? 1 : 0;   // == nonempty
    const int jl = (W > 0) ? (W - 1) : 0;

    if (enc) {
      for (int idx = tid; idx < W * 128; idx += 256) {
        int i = idx >> 7, d = idx & 127;
        S.xbuf[i * XS + d] = ldw(tok_emb + (long long)S.win_ids[i] * 128 + d)
                             + ldw(pos_emb + i * 128 + d);
      }
      __syncthreads();
      for (int l = 0; l < 2; ++l) {
        const WT* Wq = Wqkv + l * 384 * 128;
        const WT* bq = bqkv + l * 384;
        if (l == 0) {
          gemm_tok<3, 8, 128, false>(Wq, bq, 384, S.xbuf, XS, S.qh, QS, W, tid);
          __syncthreads();
          if (tid < 128) {
            int h = tid >> 5, i = tid & 31;
            if (i < W) {
              float4 q[8];
#pragma unroll
              for (int kk = 0; kk < 8; ++kk) q[kk] = *(const float4*)&S.qh[i * QS + h * 32 + kk * 4];
              int pb = (h * 32 + i) * PS;
              float m = -1e30f;
              for (int j = 0; j < W; ++j) {
                float s = 0.f;
#pragma unroll
                for (int kk = 0; kk < 8; ++kk)
                  s += dot4f(q[kk], *(const float4*)&S.qh[j * QS + 128 + h * 32 + kk * 4]);
                s *= 0.17677669529663687f;
                S.pbuf[pb + j] = s;
                m = fmaxf(m, s);
              }
              float sum = 0.f;
              for (int j = 0; j < W; ++j) { float e = expf(S.pbuf[pb + j] - m); S.pbuf[pb + j] = e; sum += e; }
              float rs = 1.0f / sum;
              for (int j = 0; j < W; ++j) S.pbuf[pb + j] *= rs;
            }
          }
          __syncthreads();
          {
            int c = tid & 127, qsub = tid >> 7, h = c >> 5;
            for (int i = qsub; i < W; i += 2) {
              float acc = 0.f;
              for (int j = 0; j < W; ++j) acc += S.pbuf[(h * 32 + i) * PS + j] * S.qh[j * QS + 256 + c];
              S.obuf[i * XS + c] = acc;
            }
          }
          __syncthreads();
          gemm_tok<2, 4, 128, false>(Wo + l * 16384, bo + l * 128, 128, S.obuf, XS, S.pbuf, XS, W, tid);
          __syncthreads();
          ln_rows(S.xbuf, S.pbuf, ln1g + l * 128, ln1b + l * 128, W, tid);
          __syncthreads();
          gemm_tok<4, 8, 128, true>(W1 + l * 512 * 128, b1 + l * 512, 512, S.xbuf, XS, S.qh, HS, W, tid);
          __syncthreads();
          gemm_tok<2, 4, 512, false>(W2 + l * 128 * 512, b2 + l * 128, 128, S.qh, HS, S.obuf, XS, W, tid);
          __syncthreads();
          ln_rows(S.xbuf, S.obuf, ln2g + l * 128, ln2b + l * 128, W, tid);
          __syncthreads();
        } else {
          // layer 2: K,V for all tokens; Q/attn/out-proj/FFN/LN only at jl
          gemm_tok<2, 8, 128, false>(Wq + 128 * 128, bq + 128, 256, S.xbuf, XS, S.qh + 128, QS, W, tid);
          __syncthreads();
          if (tid < 128)
            S.qh[jl * QS + tid] = ldw(bq + tid) + dotgf<128>(Wq + tid * 128, &S.xbuf[jl * XS]);
          __syncthreads();
          if (tid < 128) {
            int h = tid >> 5, j = tid & 31;
            float s = -1e30f;
            if (j < W) {
              s = 0.f;
#pragma unroll
              for (int kk = 0; kk < 8; ++kk)
                s += dot4f(*(const float4*)&S.qh[jl * QS + h * 32 + kk * 4],
                           *(const float4*)&S.qh[j * QS + 128 + h * 32 + kk * 4]);
              s *= 0.17677669529663687f;
            }
            float m = s;
            for (int mk = 16; mk; mk >>= 1) m = fmaxf(m, __shfl_xor(m, mk, 32));
            float e = (j < W) ? expf(s - m) : 0.f;
            float sum = e;
            for (int mk = 16; mk; mk >>= 1) sum += __shfl_xor(sum, mk, 32);
            if (j < W) S.pbuf[h * PS + j] = e * (1.0f / sum);
          }
          __syncthreads();
          if (tid < 128) {
            int h = tid >> 5;
            float acc = 0.f;
            for (int j = 0; j < W; ++j) acc += S.pbuf[h * PS + j] * S.qh[j * QS + 256 + tid];
            S.attT[tid] = acc;
          }
          __syncthreads();
          if (tid < 128)
            S.tva[tid] = ldw(bo + l * 128 + tid) + dotgf<128>(Wo + l * 16384 + tid * 128, S.attT);
          __syncthreads();
          ln_tail(&S.xbuf[jl * XS], S.tva, ln1g + l * 128, ln1b + l * 128, tid);
          __syncthreads();
          for (int j = tid; j < 512; j += 256)
            S.qh[j] = fmaxf(ldw(b1 + l * 512 + j) + dotgf<128>(W1 + (l * 512 + j) * 128, &S.xbuf[jl * XS]), 0.f);
          __syncthreads();
          if (tid < 128)
            S.tva[tid] = ldw(b2 + l * 128 + tid) + dotgf<512>(W2 + (l * 128 + tid) * 512, S.qh);
          __syncthreads();
          ln_tail(&S.xbuf[jl * XS], S.tva, ln2g + l * 128, ln2b + l * 128, tid);
          __syncthreads();
        }
      }
    }

    // proj + L2 normalize -> t1 (fp64; zero when window empty or done)
    if (tid < 64) {
      double tv = 0.0;
      if (enc) {
        double v = ldwd(projb + tid) + dotgdx<128>(projW + tid * 128, &S.xbuf[jl * XS]);
        double ss = wredsumd(v * v, 64);
        tv = v / fmax(sqrt(ss), 1e-12);
      }
      S.t1d[tid] = tv;
      P.out[(size_t)t * 4096 + row * 64 + tid] = (float)tv;
    }
    __syncthreads();

    // GRU (fp64, only when active)
    if (act) {
      for (int j = tid; j < 384; j += 256) {
        S.gild[j] = ldwd(gbih + j) + dotgd<64>(gWih + j * 64, S.t1d);
        S.ghld[j] = ldwd(gbhh + j) + dotgd<128>(gWhh + j * 128, S.hsd);
      }
      __syncthreads();
      if (tid < 128) {
        double r = 1.0 / (1.0 + exp(-(S.gild[tid] + S.ghld[tid])));
        double z = 1.0 / (1.0 + exp(-(S.gild[128 + tid] + S.ghld[128 + tid])));
        double n = tanh(S.gild[256 + tid] + r * S.ghld[256 + tid]);
        S.hsd[tid] = (1.0 - z) * n + z * S.hsd[tid];
      }
      __syncthreads();
    }

    // heads input: [next_embs(128), t1(64), h(128)] (fp64)
    {
      int ipc = ip < 0 ? 0 : (ip > 63 ? 63 : ip);
      int nt = P.token_ids[row * 64 + ipc];
      int has_in = (act && (ip < seq)) ? 1 : 0;
      for (int idx = tid; idx < 320; idx += 256) {
        double v;
        if (idx < 128)      v = has_in ? (double)ldw(tok_emb + (long long)nt * 128 + idx) : 0.0;
        else if (idx < 192) v = S.t1d[idx - 128];
        else                v = S.hsd[idx - 192];
        S.catd[idx] = v;
      }
    }
    __syncthreads();
    if (tid < 128) S.hid2d[tid] = fmax(ldwd(accb1 + tid) + dotgd<320>(accW1 + tid * 320, S.catd), 0.0);
    __syncthreads();
    head_logit(accW2, accb2, S.hid2d, &S.logitsd[0], tid);
    __syncthreads();
    if (tid < 128) S.hid2d[tid] = fmax(ldwd(emtb1 + tid) + dotgd<192>(emtW1 + tid * 192, S.catd + 128), 0.0);
    __syncthreads();
    head_logit(emtW2, emtb2, S.hid2d, &S.logitsd[1], tid);
    __syncthreads();
    if (tid < 128) S.hid2d[tid] = fmax(ldwd(evtb1 + tid) + dotgd<192>(evtW1 + tid * 192, S.catd + 128), 0.0);
    __syncthreads();
    head_logit(evtW2, evtb2, S.hid2d, &S.logitsd[2], tid);
    __syncthreads();

    // sample (partitionable JAX threefry) + state update, thread 0
    if (tid == 0) {
      unsigned k0 = S.keyts[t][0], k1 = S.keyts[t][1];
      // split(key_t, 3): k_s = full pair of tfry(key_t, (0, s))
      unsigned sk[3][2];
      tfry(k0, k1, 0u, 0u, sk[0][0], sk[0][1]);
      tfry(k0, k1, 0u, 1u, sk[1][0], sk[1][1]);
      tfry(k0, k1, 0u, 2u, sk[2][0], sk[2][1]);
      int smp[3];
      double lg[3] = {S.logitsd[0], S.logitsd[1], S.logitsd[2]};
      for (int s = 0; s < 3; ++s) {
        unsigned r0, r1;
        tfry(sk[s][0], sk[s][1], 0u, (unsigned)row, r0, r1);
        unsigned bits = r0 ^ r1;   // partitionable 32-bit random_bits = fold of the two words
        double u = (double)u01(bits);
        double p = 1.0 / (1.0 + exp(-lg[s]));
        smp[s] = (u < p) ? 1 : 0;
        P.out[131072 + (size_t)t * 192 + row * 3 + s] = (float)logsigd(smp[s] ? lg[s] : -lg[s]);
        P.out[137216 + (size_t)t * 192 + row * 3 + s] = smp[s] ? 1.0f : 0.0f;
      }
      int wl2 = wl, ip2 = ip, dn = done;
      int nonempty = (wl2 > 0) && act;
      int has_in = act && (ip2 < seq);
      int a = smp[0] && has_in;
      int e = smp[1] && nonempty;
      int v = smp[2] && nonempty;
      int none = act && !(a || e || v);
      a = a || (none && has_in);
      e = e || (none && !has_in && (wl2 > 0));
      int aeff = a && (wl2 < 32);
      int ipc = ip2 < 0 ? 0 : (ip2 > 63 ? 63 : ip2);
      int nt = P.token_ids[row * 64 + ipc];
      if (aeff) { S.win_ids[wl2] = nt; ip2 += 1; wl2 += 1; }
      int emit = e && (wl2 > 0);
      S.sI[4] += emit;
      int veff = v && (wl2 > 0);
      if (veff) {
        int w0 = S.win_ids[0];
#pragma unroll
        for (int i2 = 0; i2 < 31; ++i2) S.win_ids[i2] = S.win_ids[i2 + 1];
        S.win_ids[31] = w0;
        wl2 -= 1;
      }
      if (act && (ip2 >= seq) && (wl2 == 0)) dn = 1;
      S.sI[0] = wl2; S.sI[1] = ip2; S.sI[2] = dn;
    }
    __syncthreads();
  }
  if (tid == 0) P.out[143360 + row] = (float)S.sI[4];
}

__global__ __launch_bounds__(256) void src_main_kernel(KParams P){
  __shared__ __align__(16) Smem S;
  const int row = blockIdx.x;
  const int tid = threadIdx.x;
  // probe input dtype: bf16(1.0) first halfword = 0x3F80; f32(1.0) low half = 0
  const bool isb = (((const unsigned short*)P.ln1g)[0] == (unsigned short)0x3F80);
  if (isb) run_all<unsigned short>(P, S, row, tid);
  else     run_all<float>(P, S, row, tid);
}

extern "C" void kernel_launch(void* const* d_in, const int* in_sizes, int n_in,
                              void* d_out, int out_size, void* d_ws, size_t ws_size,
                              hipStream_t stream) {
  KParams P;
  P.token_ids = (const int*)d_in[0];
  P.pad = (const unsigned char*)d_in[1];
  P.tok_emb = d_in[4];  P.pos_emb = d_in[5];
  P.Wqkv = d_in[6];     P.bqkv = d_in[7];
  P.Wo = d_in[8];       P.bo = d_in[9];
  P.ln1g = d_in[10];    P.ln1b = d_in[11];
  P.W1 = d_in[12];      P.b1 = d_in[13];
  P.W2 = d_in[14];      P.b2 = d_in[15];
  P.ln2g = d_in[16];    P.ln2b = d_in[17];
  P.projW = d_in[18];   P.projb = d_in[19];
  P.gWih = d_in[20];    P.gWhh = d_in[21];
  P.gbih = d_in[22];    P.gbhh = d_in[23];
  P.accW1 = d_in[24];   P.accb1 = d_in[25];
  P.accW2 = d_in[26];   P.accb2 = d_in[27];
  P.emtW1 = d_in[28];   P.emtb1 = d_in[29];
  P.emtW2 = d_in[30];   P.emtb2 = d_in[31];
  P.evtW1 = d_in[32];   P.evtb1 = d_in[33];
  P.evtW2 = d_in[34];   P.evtb2 = d_in[35];
  P.out = (float*)d_out;
  hipLaunchKernelGGL(src_main_kernel, dim3(64), dim3(256), 0, stream, P);
}

// Round 5
// 5579.828 us; speedup vs baseline: 1.0789x; 1.0789x over previous
//
#include <hip/hip_runtime.h>
#include <hip/hip_bf16.h>

// ShiftReduceCompressor: persistent kernel, 1 block per batch row (B=64),
// 1024 threads (16 waves), full 32-iteration scan in-kernel. Encoder fp32,
// sampling-critical tail fp64 (unchanged numerics from the passing round-4
// kernel). Partitionable JAX threefry (exact). Weights staged bf16->f32 in
// d_ws when ws_size permits (fallback: direct typed reads).

#define XS 132   // x / obuf row stride (floats, 16B-aligned)
#define QS 388   // qkv row stride
#define HS 516   // ffn hidden row stride
#define PS 36    // prob row stride
#define NW 16    // waves per block

struct KParams {
  const int* token_ids;
  const unsigned char* pad;
  const void *tok_emb, *pos_emb, *Wqkv, *bqkv, *Wo, *bo, *ln1g, *ln1b;
  const void *W1, *b1, *W2, *b2, *ln2g, *ln2b, *projW, *projb;
  const void *gWih, *gWhh, *gbih, *gbhh;
  const void *accW1, *accb1, *accW2, *accb2;
  const void *emtW1, *emtb1, *emtW2, *emtb2;
  const void *evtW1, *evtb1, *evtW2, *evtb2;
  const int* flag;   // null -> probe ln1g for dtype; else *flag = emb-is-bf16
  float* out;
};

struct Smem {
  float xbuf[32 * XS];
  float qh[32 * HS];
  float obuf[32 * XS];
  float pbuf[4608];
  float attT[128];
  float tva[128];
  double gild[384];
  double ghld[384];
  double hsd[128];
  double t1d[64];
  double catd[320];
  double hid2d[384];
  double logitsd[3];
  int win_ids[32];
  int sI[6];                 // 0 win_len, 1 input_pos, 2 done, 3 seq_len, 4 emit_sum
  unsigned keyts[32][2];
};

// ---------- typed loads (f32 or bf16) ----------
__device__ __forceinline__ float ldw(const float* p){ return *p; }
__device__ __forceinline__ float ldw(const unsigned short* p){
  return __uint_as_float(((unsigned)*p) << 16);
}
__device__ __forceinline__ float4 ld4(const float* p){ return *(const float4*)p; }
__device__ __forceinline__ float4 ld4(const unsigned short* p){
  ushort4 u = *(const ushort4*)p;
  return make_float4(__uint_as_float((unsigned)u.x << 16),
                     __uint_as_float((unsigned)u.y << 16),
                     __uint_as_float((unsigned)u.z << 16),
                     __uint_as_float((unsigned)u.w << 16));
}
template<typename WT>
__device__ __forceinline__ double ldwd(const WT* p){ return (double)ldw(p); }

__device__ __forceinline__ float temb(const void* te, int isb, long long idx){
  if (isb) return __uint_as_float(((unsigned)((const unsigned short*)te)[idx]) << 16);
  return ((const float*)te)[idx];
}

// ---------- JAX threefry2x32 (20 rounds) ----------
__device__ __forceinline__ void tfry(unsigned k0, unsigned k1, unsigned x0, unsigned x1,
                                     unsigned &o0, unsigned &o1){
  unsigned ks2 = k0 ^ k1 ^ 0x1BD11BDAu;
  unsigned x = x0 + k0, y = x1 + k1;
#define TFR(r) { x += y; y = (y << r) | (y >> (32 - r)); y ^= x; }
  TFR(13) TFR(15) TFR(26) TFR(6)  x += k1;  y += ks2 + 1u;
  TFR(17) TFR(29) TFR(16) TFR(24) x += ks2; y += k0 + 2u;
  TFR(13) TFR(15) TFR(26) TFR(6)  x += k0;  y += k1 + 3u;
  TFR(17) TFR(29) TFR(16) TFR(24) x += k1;  y += ks2 + 4u;
  TFR(13) TFR(15) TFR(26) TFR(6)  x += ks2; y += k0 + 5u;
#undef TFR
  o0 = x; o1 = y;
}

__device__ __forceinline__ float u01(unsigned bits){
  return __uint_as_float((bits >> 9) | 0x3f800000u) - 1.0f;
}
__device__ __forceinline__ double logsigd(double x){
  return fmin(x, 0.0) - log1p(exp(-fabs(x)));
}
__device__ __forceinline__ float wredsum(float v, int width){
  for (int m = width >> 1; m > 0; m >>= 1) v += __shfl_xor(v, m, width);
  return v;
}
__device__ __forceinline__ double wredsumd(double v, int width){
  for (int m = width >> 1; m > 0; m >>= 1) v += __shfl_xor(v, m, width);
  return v;
}
__device__ __forceinline__ float dot4f(float4 a, float4 b){
  return a.x*b.x + a.y*b.y + a.z*b.z + a.w*b.w;
}

// out[tok][j] = bias[j] + sum_k W[j][k]*x[tok][k]; lane=j mod 64, NW waves.
template<int J2, int T, int K, bool RELU, typename WT>
__device__ void gemm_tok(const WT* __restrict__ Wm, const WT* __restrict__ bias,
                         int J, const float* __restrict__ xl, int xs,
                         float* __restrict__ ol, int os, int ntok, int tid)
{
  const int lane = tid & 63, wid = tid >> 6;
  const int JBG = J / (64 * J2);
  const int ntt = (ntok + T - 1) / T;
  for (int item = wid; item < JBG * ntt; item += NW) {
    const int jg = item % JBG, tt = item / JBG;
    const int j0 = jg * 64 * J2 + lane;
    float acc[J2][T];
#pragma unroll
    for (int u = 0; u < J2; ++u)
#pragma unroll
      for (int t = 0; t < T; ++t) acc[u][t] = 0.f;
    const float* xr = xl + tt * T * xs;
#pragma unroll 4
    for (int k = 0; k < K; k += 4) {
      float4 xv[T];
#pragma unroll
      for (int t = 0; t < T; ++t) xv[t] = *(const float4*)(xr + t * xs + k);
#pragma unroll
      for (int u = 0; u < J2; ++u) {
        float4 w = ld4(Wm + (j0 + u * 64) * K + k);
#pragma unroll
        for (int t = 0; t < T; ++t)
          acc[u][t] += w.x * xv[t].x + w.y * xv[t].y + w.z * xv[t].z + w.w * xv[t].w;
      }
    }
#pragma unroll
    for (int u = 0; u < J2; ++u) {
      float bj = ldw(bias + j0 + u * 64);
#pragma unroll
      for (int t = 0; t < T; ++t) {
        int tok = tt * T + t;
        if (tok < ntok) {
          float v = acc[u][t] + bj;
          if (RELU) v = fmaxf(v, 0.f);
          ol[tok * os + j0 + u * 64] = v;
        }
      }
    }
  }
}

template<int K, typename WT>
__device__ __forceinline__ float dotgf(const WT* __restrict__ w, const float* x){
  float acc = 0.f;
#pragma unroll 8
  for (int k = 0; k < K; k += 4) {
    float4 wv = ld4(w + k);
    acc += wv.x * x[k] + wv.y * x[k+1] + wv.z * x[k+2] + wv.w * x[k+3];
  }
  return acc;
}
template<int K, typename WT>
__device__ __forceinline__ double dotgd(const WT* __restrict__ w, const double* x){
  double acc = 0.0;
#pragma unroll 4
  for (int k = 0; k < K; k += 4) {
    float4 wv = ld4(w + k);
    acc += (double)wv.x * x[k] + (double)wv.y * x[k+1]
         + (double)wv.z * x[k+2] + (double)wv.w * x[k+3];
  }
  return acc;
}
template<int K, typename WT>
__device__ __forceinline__ double dotgdx(const WT* __restrict__ w, const float* x){
  double acc = 0.0;
#pragma unroll 4
  for (int k = 0; k < K; k += 4) {
    float4 wv = ld4(w + k);
    acc += (double)wv.x * (double)x[k] + (double)wv.y * (double)x[k+1]
         + (double)wv.z * (double)x[k+2] + (double)wv.w * (double)x[k+3];
  }
  return acc;
}

// post-norm LN over D=128 for rows <W (uses threads 0..255)
template<typename WT>
__device__ void ln_rows(float* xb, const float* ob, const WT* __restrict__ g,
                        const WT* __restrict__ bb, int W, int tid){
  if (tid >= 256) return;
  const int i = tid >> 3, sub = tid & 7;
  const int base = i * XS + sub * 16;
  float y[16];
  float s = 0.f;
#pragma unroll
  for (int u = 0; u < 16; ++u) { y[u] = xb[base + u] + ob[base + u]; s += y[u]; }
  s = wredsum(s, 8);
  const float m = s * (1.0f / 128.0f);
  float vs = 0.f;
#pragma unroll
  for (int u = 0; u < 16; ++u) { float d = y[u] - m; vs += d * d; }
  vs = wredsum(vs, 8);
  const float rstd = 1.0f / sqrtf(vs * (1.0f / 128.0f) + 1e-5f);
  if (i < W) {
#pragma unroll
    for (int u = 0; u < 16; ++u)
      xb[base + u] = (y[u] - m) * rstd * ldw(g + sub * 16 + u) + ldw(bb + sub * 16 + u);
  }
}

template<typename WT>
__device__ __forceinline__ void ln_tail(float* xrow, const float* add,
                                        const WT* __restrict__ g,
                                        const WT* __restrict__ bb, int tid){
  if (tid < 64) {
    float y0 = xrow[tid] + add[tid];
    float y1 = xrow[64 + tid] + add[64 + tid];
    float m = wredsum(y0 + y1, 64) * (1.0f / 128.0f);
    float d0 = y0 - m, d1 = y1 - m;
    float rstd = 1.0f / sqrtf(wredsum(d0 * d0 + d1 * d1, 64) * (1.0f / 128.0f) + 1e-5f);
    xrow[tid] = d0 * rstd * ldw(g + tid) + ldw(bb + tid);
    xrow[64 + tid] = d1 * rstd * ldw(g + 64 + tid) + ldw(bb + 64 + tid);
  }
}

template<typename WT>
__device__ void run_all(const KParams& P, Smem& S, int row, int tid, int isbEmb){
  const WT* pos_emb = (const WT*)P.pos_emb;
  const WT* Wqkv = (const WT*)P.Wqkv;   const WT* bqkv = (const WT*)P.bqkv;
  const WT* Wo = (const WT*)P.Wo;       const WT* bo = (const WT*)P.bo;
  const WT* ln1g = (const WT*)P.ln1g;   const WT* ln1b = (const WT*)P.ln1b;
  const WT* W1 = (const WT*)P.W1;       const WT* b1 = (const WT*)P.b1;
  const WT* W2 = (const WT*)P.W2;       const WT* b2 = (const WT*)P.b2;
  const WT* ln2g = (const WT*)P.ln2g;   const WT* ln2b = (const WT*)P.ln2b;
  const WT* projW = (const WT*)P.projW; const WT* projb = (const WT*)P.projb;
  const WT* gWih = (const WT*)P.gWih;   const WT* gWhh = (const WT*)P.gWhh;
  const WT* gbih = (const WT*)P.gbih;   const WT* gbhh = (const WT*)P.gbhh;
  const WT* accW1 = (const WT*)P.accW1; const WT* accb1 = (const WT*)P.accb1;
  const WT* accW2 = (const WT*)P.accW2; const WT* accb2 = (const WT*)P.accb2;
  const WT* emtW1 = (const WT*)P.emtW1; const WT* emtb1 = (const WT*)P.emtb1;
  const WT* emtW2 = (const WT*)P.emtW2; const WT* emtb2 = (const WT*)P.emtb2;
  const WT* evtW1 = (const WT*)P.evtW1; const WT* evtb1 = (const WT*)P.evtb1;
  const WT* evtW2 = (const WT*)P.evtW2; const WT* evtb2 = (const WT*)P.evtb2;

  // ---- init ----
  if (tid == 0) {
    int seq = 0;
    for (int l = 0; l < 64; ++l) seq += (P.pad[row * 64 + l] == 0);
    S.sI[0] = 0; S.sI[1] = 0; S.sI[2] = (seq == 0) ? 1 : 0; S.sI[3] = seq; S.sI[4] = 0;
  }
  if (tid < 128) S.hsd[tid] = 0.0;
  if (tid < 32) {
    S.win_ids[tid] = 0;
    unsigned a0, a1;
    tfry(0u, 42u, 0u, (unsigned)tid, a0, a1);   // partitionable split of key(42)
    S.keyts[tid][0] = a0; S.keyts[tid][1] = a1;
  }
  __syncthreads();

  for (int t = 0; t < 32; ++t) {
    const int wl = S.sI[0], ip = S.sI[1], done = S.sI[2], seq = S.sI[3];
    const int act = !done;
    const int W = wl;
    const int enc = (act && wl > 0) ? 1 : 0;   // == nonempty
    const int jl = (W > 0) ? (W - 1) : 0;

    if (enc) {
      for (int idx = tid; idx < W * 128; idx += 1024) {
        int i = idx >> 7, d = idx & 127;
        S.xbuf[i * XS + d] = temb(P.tok_emb, isbEmb, (long long)S.win_ids[i] * 128 + d)
                             + ldw(pos_emb + i * 128 + d);
      }
      __syncthreads();
      // ---------------- layer 0 (full) ----------------
      {
        const WT* Wq = Wqkv;
        const WT* bq = bqkv;
        gemm_tok<3, 4, 128, false>(Wq, bq, 384, S.xbuf, XS, S.qh, QS, W, tid);
        __syncthreads();
        if (tid < 128) {
          int h = tid >> 5, i = tid & 31;
          if (i < W) {
            float4 q[8];
#pragma unroll
            for (int kk = 0; kk < 8; ++kk) q[kk] = *(const float4*)&S.qh[i * QS + h * 32 + kk * 4];
            int pb = (h * 32 + i) * PS;
            float m = -1e30f;
            for (int j = 0; j < W; ++j) {
              float s = 0.f;
#pragma unroll
              for (int kk = 0; kk < 8; ++kk)
                s += dot4f(q[kk], *(const float4*)&S.qh[j * QS + 128 + h * 32 + kk * 4]);
              s *= 0.17677669529663687f;
              S.pbuf[pb + j] = s;
              m = fmaxf(m, s);
            }
            float sum = 0.f;
            for (int j = 0; j < W; ++j) { float e = expf(S.pbuf[pb + j] - m); S.pbuf[pb + j] = e; sum += e; }
            float rs = 1.0f / sum;
            for (int j = 0; j < W; ++j) S.pbuf[pb + j] *= rs;
          }
        }
        __syncthreads();
        {
          int c = tid & 127, qsub = tid >> 7, h = c >> 5;   // 8 token-groups
          for (int i = qsub; i < W; i += 8) {
            float acc = 0.f;
            for (int j = 0; j < W; ++j) acc += S.pbuf[(h * 32 + i) * PS + j] * S.qh[j * QS + 256 + c];
            S.obuf[i * XS + c] = acc;
          }
        }
        __syncthreads();
        gemm_tok<1, 4, 128, false>(Wo, bo, 128, S.obuf, XS, S.pbuf, XS, W, tid);
        __syncthreads();
        ln_rows(S.xbuf, S.pbuf, ln1g, ln1b, W, tid);
        __syncthreads();
        gemm_tok<2, 4, 128, true>(W1, b1, 512, S.xbuf, XS, S.qh, HS, W, tid);
        __syncthreads();
        gemm_tok<1, 4, 512, false>(W2, b2, 128, S.qh, HS, S.obuf, XS, W, tid);
        __syncthreads();
        ln_rows(S.xbuf, S.obuf, ln2g, ln2b, W, tid);
        __syncthreads();
      }
      // ---------------- layer 1 (last-token only) ----------------
      {
        const WT* Wq = Wqkv + 384 * 128;
        const WT* bq = bqkv + 384;
        gemm_tok<1, 4, 128, false>(Wq + 128 * 128, bq + 128, 256, S.xbuf, XS, S.qh + 128, QS, W, tid);
        __syncthreads();
        if (tid < 128)
          S.qh[jl * QS + tid] = ldw(bq + tid) + dotgf<128>(Wq + tid * 128, &S.xbuf[jl * XS]);
        __syncthreads();
        if (tid < 128) {
          int h = tid >> 5, j = tid & 31;
          float s = -1e30f;
          if (j < W) {
            s = 0.f;
#pragma unroll
            for (int kk = 0; kk < 8; ++kk)
              s += dot4f(*(const float4*)&S.qh[jl * QS + h * 32 + kk * 4],
                         *(const float4*)&S.qh[j * QS + 128 + h * 32 + kk * 4]);
            s *= 0.17677669529663687f;
          }
          float m = s;
          for (int mk = 16; mk; mk >>= 1) m = fmaxf(m, __shfl_xor(m, mk, 32));
          float e = (j < W) ? expf(s - m) : 0.f;
          float sum = e;
          for (int mk = 16; mk; mk >>= 1) sum += __shfl_xor(sum, mk, 32);
          if (j < W) S.pbuf[h * PS + j] = e * (1.0f / sum);
        }
        __syncthreads();
        if (tid < 128) {
          int h = tid >> 5;
          float acc = 0.f;
          for (int j = 0; j < W; ++j) acc += S.pbuf[h * PS + j] * S.qh[j * QS + 256 + tid];
          S.attT[tid] = acc;
        }
        __syncthreads();
        if (tid < 128)
          S.tva[tid] = ldw(bo + 128 + tid) + dotgf<128>(Wo + 16384 + tid * 128, S.attT);
        __syncthreads();
        ln_tail(&S.xbuf[jl * XS], S.tva, ln1g + 128, ln1b + 128, tid);
        __syncthreads();
        if (tid < 512)
          S.qh[tid] = fmaxf(ldw(b1 + 512 + tid) + dotgf<128>(W1 + (512 + tid) * 128, &S.xbuf[jl * XS]), 0.f);
        __syncthreads();
        if (tid < 128)
          S.tva[tid] = ldw(b2 + 128 + tid) + dotgf<512>(W2 + (128 + tid) * 512, S.qh);
        __syncthreads();
        ln_tail(&S.xbuf[jl * XS], S.tva, ln2g + 128, ln2b + 128, tid);
        __syncthreads();
      }
    }

    // proj + L2 normalize -> t1 (fp64; zero when window empty or done)
    if (tid < 64) {
      double tv = 0.0;
      if (enc) {
        double v = ldwd(projb + tid) + dotgdx<128>(projW + tid * 128, &S.xbuf[jl * XS]);
        double ss = wredsumd(v * v, 64);
        tv = v / fmax(sqrt(ss), 1e-12);
      }
      S.t1d[tid] = tv;
      P.out[(size_t)t * 4096 + row * 64 + tid] = (float)tv;
    }
    __syncthreads();

    // GRU (fp64, only when active): gil and ghl concurrently
    if (act) {
      if (tid < 384)
        S.gild[tid] = ldwd(gbih + tid) + dotgd<64>(gWih + tid * 64, S.t1d);
      else if (tid < 768) {
        int j = tid - 384;
        S.ghld[j] = ldwd(gbhh + j) + dotgd<128>(gWhh + j * 128, S.hsd);
      }
      __syncthreads();
      if (tid < 128) {
        double r = 1.0 / (1.0 + exp(-(S.gild[tid] + S.ghld[tid])));
        double z = 1.0 / (1.0 + exp(-(S.gild[128 + tid] + S.ghld[128 + tid])));
        double n = tanh(S.gild[256 + tid] + r * S.ghld[256 + tid]);
        S.hsd[tid] = (1.0 - z) * n + z * S.hsd[tid];
      }
      __syncthreads();
    }

    // heads input: [next_embs(128), t1(64), h(128)] (fp64)
    {
      int ipc = ip < 0 ? 0 : (ip > 63 ? 63 : ip);
      int nt = P.token_ids[row * 64 + ipc];
      int has_in = (act && (ip < seq)) ? 1 : 0;
      if (tid < 320) {
        double v;
        if (tid < 128)      v = has_in ? (double)temb(P.tok_emb, isbEmb, (long long)nt * 128 + tid) : 0.0;
        else if (tid < 192) v = S.t1d[tid - 128];
        else                v = S.hsd[tid - 192];
        S.catd[tid] = v;
      }
    }
    __syncthreads();
    // all three head hidden layers concurrently
    if (tid < 128) {
      S.hid2d[tid] = fmax(ldwd(accb1 + tid) + dotgd<320>(accW1 + tid * 320, S.catd), 0.0);
    } else if (tid < 256) {
      int j = tid - 128;
      S.hid2d[128 + j] = fmax(ldwd(emtb1 + j) + dotgd<192>(emtW1 + j * 192, S.catd + 128), 0.0);
    } else if (tid < 384) {
      int j = tid - 256;
      S.hid2d[256 + j] = fmax(ldwd(evtb1 + j) + dotgd<192>(evtW1 + j * 192, S.catd + 128), 0.0);
    }
    __syncthreads();
    // three logits concurrently (waves 0,1,2)
    {
      int hw = tid >> 6;
      if (hw < 3) {
        int ln = tid & 63;
        const WT* w2 = (hw == 0) ? accW2 : ((hw == 1) ? emtW2 : evtW2);
        const WT* b2p = (hw == 0) ? accb2 : ((hw == 1) ? emtb2 : evtb2);
        double pp = S.hid2d[hw * 128 + ln] * ldwd(w2 + ln)
                  + S.hid2d[hw * 128 + 64 + ln] * ldwd(w2 + 64 + ln);
        pp = wredsumd(pp, 64);
        if (ln == 0) S.logitsd[hw] = pp + ldwd(b2p);
      }
    }
    __syncthreads();

    // sample (partitionable JAX threefry) + state update, thread 0
    if (tid == 0) {
      unsigned k0 = S.keyts[t][0], k1 = S.keyts[t][1];
      unsigned sk[3][2];
      tfry(k0, k1, 0u, 0u, sk[0][0], sk[0][1]);
      tfry(k0, k1, 0u, 1u, sk[1][0], sk[1][1]);
      tfry(k0, k1, 0u, 2u, sk[2][0], sk[2][1]);
      int smp[3];
      double lg[3] = {S.logitsd[0], S.logitsd[1], S.logitsd[2]};
      for (int s = 0; s < 3; ++s) {
        unsigned r0, r1;
        tfry(sk[s][0], sk[s][1], 0u, (unsigned)row, r0, r1);
        unsigned bits = r0 ^ r1;
        double u = (double)u01(bits);
        double p = 1.0 / (1.0 + exp(-lg[s]));
        smp[s] = (u < p) ? 1 : 0;
        P.out[131072 + (size_t)t * 192 + row * 3 + s] = (float)logsigd(smp[s] ? lg[s] : -lg[s]);
        P.out[137216 + (size_t)t * 192 + row * 3 + s] = smp[s] ? 1.0f : 0.0f;
      }
      int wl2 = wl, ip2 = ip, dn = done;
      int nonempty = (wl2 > 0) && act;
      int has_in = act && (ip2 < seq);
      int a = smp[0] && has_in;
      int e = smp[1] && nonempty;
      int v = smp[2] && nonempty;
      int none = act && !(a || e || v);
      a = a || (none && has_in);
      e = e || (none && !has_in && (wl2 > 0));
      int aeff = a && (wl2 < 32);
      int ipc = ip2 < 0 ? 0 : (ip2 > 63 ? 63 : ip2);
      int nt = P.token_ids[row * 64 + ipc];
      if (aeff) { S.win_ids[wl2] = nt; ip2 += 1; wl2 += 1; }
      int emit = e && (wl2 > 0);
      S.sI[4] += emit;
      int veff = v && (wl2 > 0);
      if (veff) {
        int w0 = S.win_ids[0];
#pragma unroll
        for (int i2 = 0; i2 < 31; ++i2) S.win_ids[i2] = S.win_ids[i2 + 1];
        S.win_ids[31] = w0;
        wl2 -= 1;
      }
      if (act && (ip2 >= seq) && (wl2 == 0)) dn = 1;
      S.sI[0] = wl2; S.sI[1] = ip2; S.sI[2] = dn;
    }
    __syncthreads();
  }
  if (tid == 0) P.out[143360 + row] = (float)S.sI[4];
}

__global__ __launch_bounds__(1024) void src_main_kernel(KParams P){
  __shared__ __align__(16) Smem S;
  const int row = blockIdx.x;
  const int tid = threadIdx.x;
  if (P.flag) {
    // weights pre-staged as f32 in d_ws; emb dtype flag written by cvt
    run_all<float>(P, S, row, tid, *P.flag);
  } else {
    const bool isb = (((const unsigned short*)P.ln1g)[0] == (unsigned short)0x3F80);
    if (isb) run_all<unsigned short>(P, S, row, tid, 1);
    else     run_all<float>(P, S, row, tid, 0);
  }
}

// ---- one-time bf16->f32 weight staging into d_ws ----
struct CvtEnt { const void* src; int n; int off; };
struct CvtParams { CvtEnt e[31]; float* dst; int* flag; const unsigned short* probe; };

__global__ __launch_bounds__(256) void cvt_kernel(CvtParams C){
  const bool isb = (C.probe[0] == (unsigned short)0x3F80);
  if (blockIdx.x == 0 && threadIdx.x == 0) *C.flag = isb ? 1 : 0;
  const int gid = blockIdx.x * 256 + threadIdx.x;
  const int gstr = gridDim.x * 256;
  for (int e = 0; e < 31; ++e) {
    const int n = C.e[e].n;
    float* d = C.dst + C.e[e].off;
    if (isb) {
      const unsigned short* s = (const unsigned short*)C.e[e].src;
      for (int i = gid; i < n; i += gstr) d[i] = __uint_as_float(((unsigned)s[i]) << 16);
    } else {
      const float* s = (const float*)C.e[e].src;
      for (int i = gid; i < n; i += gstr) d[i] = s[i];
    }
  }
}

extern "C" void kernel_launch(void* const* d_in, const int* in_sizes, int n_in,
                              void* d_out, int out_size, void* d_ws, size_t ws_size,
                              hipStream_t stream) {
  static const int counts[31] = {
    4096, 98304, 768, 32768, 256, 256, 256, 131072, 1024, 131072,
    256, 256, 256, 8192, 64, 24576, 49152, 384, 384, 40960,
    128, 128, 1, 24576, 128, 128, 1, 24576, 128, 128, 1
  };
  size_t need = 0;
  for (int i = 0; i < 31; ++i) need += (size_t)((counts[i] + 3) & ~3);
  need = (need + 4) * sizeof(float);   // + flag slot

  KParams P;
  P.token_ids = (const int*)d_in[0];
  P.pad = (const unsigned char*)d_in[1];
  P.tok_emb = d_in[4];
  P.out = (float*)d_out;

  if (ws_size >= need) {
    float* wsf = (float*)d_ws;
    CvtParams C;
    const float* fp[31];
    int off = 0;
    for (int i = 0; i < 31; ++i) {
      C.e[i].src = d_in[5 + i];
      C.e[i].n = counts[i];
      C.e[i].off = off;
      fp[i] = wsf + off;
      off += (counts[i] + 3) & ~3;
    }
    C.dst = wsf;
    C.flag = (int*)(wsf + off);
    C.probe = (const unsigned short*)d_in[10];   // ln1g (ones)
    hipLaunchKernelGGL(cvt_kernel, dim3(128), dim3(256), 0, stream, C);

    P.flag = (const int*)(wsf + off);
    P.pos_emb = fp[0];  P.Wqkv = fp[1];  P.bqkv = fp[2];  P.Wo = fp[3];   P.bo = fp[4];
    P.ln1g = fp[5];     P.ln1b = fp[6];  P.W1 = fp[7];    P.b1 = fp[8];   P.W2 = fp[9];
    P.b2 = fp[10];      P.ln2g = fp[11]; P.ln2b = fp[12]; P.projW = fp[13]; P.projb = fp[14];
    P.gWih = fp[15];    P.gWhh = fp[16]; P.gbih = fp[17]; P.gbhh = fp[18];
    P.accW1 = fp[19];   P.accb1 = fp[20]; P.accW2 = fp[21]; P.accb2 = fp[22];
    P.emtW1 = fp[23];   P.emtb1 = fp[24]; P.emtW2 = fp[25]; P.emtb2 = fp[26];
    P.evtW1 = fp[27];   P.evtb1 = fp[28]; P.evtW2 = fp[29]; P.evtb2 = fp[30];
  } else {
    P.flag = nullptr;
    P.pos_emb = d_in[5];
    P.Wqkv = d_in[6];   P.bqkv = d_in[7];
    P.Wo = d_in[8];     P.bo = d_in[9];
    P.ln1g = d_in[10];  P.ln1b = d_in[11];
    P.W1 = d_in[12];    P.b1 = d_in[13];
    P.W2 = d_in[14];    P.b2 = d_in[15];
    P.ln2g = d_in[16];  P.ln2b = d_in[17];
    P.projW = d_in[18]; P.projb = d_in[19];
    P.gWih = d_in[20];  P.gWhh = d_in[21];
    P.gbih = d_in[22];  P.gbhh = d_in[23];
    P.accW1 = d_in[24]; P.accb1 = d_in[25];
    P.accW2 = d_in[26]; P.accb2 = d_in[27];
    P.emtW1 = d_in[28]; P.emtb1 = d_in[29];
    P.emtW2 = d_in[30]; P.emtb2 = d_in[31];
    P.evtW1 = d_in[32]; P.evtb1 = d_in[33];
    P.evtW2 = d_in[34]; P.evtb2 = d_in[35];
  }
  hipLaunchKernelGGL(src_main_kernel, dim3(64), dim3(1024), 0, stream, P);
}